// Round 1
// baseline (193.931 us; speedup 1.0000x reference)
//
#include <hip/hip_runtime.h>
#include <hip/hip_bf16.h>
#include <stdint.h>
#include <stddef.h>

typedef __bf16 bf16;
typedef __attribute__((ext_vector_type(4))) __bf16 bf16x4;
typedef __attribute__((ext_vector_type(8))) __bf16 bf16x8;
typedef __attribute__((ext_vector_type(4))) float f32x4;

#define BATCH 4096
#define DIM 1024
#define ODIM 1024
#define K3 3072   // 3 * DIM (x^3 | x^2 | x)

// workspace layout (bytes)
#define WS_P      0          // bf16 [4096][3072] = 25165824
#define WS_CB     25165824   // bf16 [1024][3072] = 6291456
#define WS_BIAS   31457280   // f32  [1024]
#define WS_PMIN   31461376   // f32  [64][1024]
#define WS_PMAX   31723520   // f32  [64][1024]
#define WS_MINV   31985664   // f32  [1024]
#define WS_SCALE  31989760   // f32  [1024]

#define ASYNC16(g, l)                                                          \
  __builtin_amdgcn_global_load_lds(                                            \
      (__attribute__((address_space(1))) void*)(g),                            \
      (__attribute__((address_space(3))) void*)(l), 16, 0, 0)

// ---- kernel 1: per-chunk column min/max (64 chunks of 64 rows) ----
__global__ void k_minmax_part(const float* __restrict__ x,
                              float* __restrict__ pmin,
                              float* __restrict__ pmax) {
  int col = blockIdx.x * 256 + threadIdx.x;
  int ch = blockIdx.y;
  const float* p = x + (size_t)ch * 64 * DIM + col;
  float mn = 1e30f, mx = -1e30f;
#pragma unroll 4
  for (int r = 0; r < 64; ++r) {
    float v = p[(size_t)r * DIM];
    mn = fminf(mn, v);
    mx = fmaxf(mx, v);
  }
  pmin[ch * DIM + col] = mn;
  pmax[ch * DIM + col] = mx;
}

// ---- kernel 2: final reduce + scale ----
__global__ void k_minmax_final(const float* __restrict__ pmin,
                               const float* __restrict__ pmax,
                               float* __restrict__ minv,
                               float* __restrict__ scale) {
  int col = blockIdx.x * 256 + threadIdx.x;
  float mn = 1e30f, mx = -1e30f;
#pragma unroll 8
  for (int ch = 0; ch < 64; ++ch) {
    mn = fminf(mn, pmin[ch * DIM + col]);
    mx = fmaxf(mx, pmax[ch * DIM + col]);
  }
  minv[col] = mn;
  scale[col] = 1.0f / (mx - mn);
}

// ---- kernel 3: normalized powers -> bf16 P[b][p*1024+d], p=0:x^3,1:x^2,2:x ----
__global__ void k_powers(const float* __restrict__ x,
                         const float* __restrict__ minv,
                         const float* __restrict__ scale,
                         bf16* __restrict__ P) {
  int idx = blockIdx.x * 256 + threadIdx.x;  // over BATCH * (DIM/4)
  int b = idx >> 8;
  int d = (idx & 255) << 2;
  f32x4 xv = *(const f32x4*)(x + (size_t)b * DIM + d);
  f32x4 mn = *(const f32x4*)(minv + d);
  f32x4 sc = *(const f32x4*)(scale + d);
  bf16x4 o3, o2, o1;
#pragma unroll
  for (int j = 0; j < 4; ++j) {
    float xn = (xv[j] - mn[j]) * sc[j];
    float x2 = xn * xn;
    float x3 = x2 * xn;
    o3[j] = (bf16)x3;
    o2[j] = (bf16)x2;
    o1[j] = (bf16)xn;
  }
  size_t base = (size_t)b * K3 + d;
  *(bf16x4*)(P + base) = o3;
  *(bf16x4*)(P + base + 1024) = o2;
  *(bf16x4*)(P + base + 2048) = o1;
}

// ---- kernel 4: spline coeff reduce -> bf16 CB[o][p*1024+d] + bias[o] ----
__global__ void k_coeffs(const float* __restrict__ sp,
                         bf16* __restrict__ CB,
                         float* __restrict__ bias) {
  int d = blockIdx.x * 256 + threadIdx.x;
  int o = blockIdx.y;
  const float* p = sp + ((size_t)o * DIM + d) * 16;  // [d][s=4][p=4]
  f32x4 s = {0.f, 0.f, 0.f, 0.f};
#pragma unroll
  for (int i = 0; i < 4; ++i) s += *(const f32x4*)(p + i * 4);
  size_t cb = (size_t)o * K3 + d;
  CB[cb] = (bf16)s[0];          // coeff of x^3
  CB[cb + 1024] = (bf16)s[1];   // coeff of x^2
  CB[cb + 2048] = (bf16)s[2];   // coeff of x
  // block-reduce s[3] -> bias[o]
  float v = s[3];
#pragma unroll
  for (int off = 32; off > 0; off >>= 1) v += __shfl_down(v, off, 64);
  __shared__ float red[4];
  int lane = threadIdx.x & 63, w = threadIdx.x >> 6;
  if (lane == 0) red[w] = v;
  __syncthreads();
  if (threadIdx.x == 0) atomicAdd(bias + o, red[0] + red[1] + red[2] + red[3]);
}

// ---- kernel 5: GEMM out[b][o] = P[b][:] . CB[o][:] + bias[o] ----
// 128x128 tile, BK=32, 256 threads = 4 waves (2x2 quadrants of 64x64),
// each wave 4x4 frags of mfma_f32_16x16x32_bf16.
__global__ __launch_bounds__(256) void k_gemm(const bf16* __restrict__ P,
                                              const bf16* __restrict__ CBm,
                                              const float* __restrict__ bias,
                                              float* __restrict__ out) {
  __shared__ bf16 sA[128 * 32];  // [row][k] rows of 64B
  __shared__ bf16 sB[128 * 32];

  const int tid = threadIdx.x;
  const int wave = tid >> 6;
  const int lane = tid & 63;
  const int bm = blockIdx.x * 128;
  const int bn = blockIdx.y * 128;
  const int wr = (wave >> 1) * 64;  // wave row quadrant
  const int wc = (wave & 1) * 64;   // wave col quadrant

  // staging: wave covers LDS bytes [wave*2048, wave*2048+2048) in two 1024B issues
  const int off0 = wave * 2048 + lane * 16;
  const int r0 = off0 >> 6, c0 = off0 & 63;
  const int off1 = off0 + 1024;
  const int r1 = off1 >> 6, c1 = off1 & 63;

  const char* gA = (const char*)P;
  const char* gB = (const char*)CBm;
  char* lA = (char*)sA;
  char* lB = (char*)sB;
  const size_t rowbytes = (size_t)K3 * 2;  // 6144

  f32x4 acc[4][4] = {};

  const int mrow = lane & 15;
  const int koff = (lane >> 4) * 8;  // k-element offset within BK=32

  for (int k0 = 0; k0 < K3; k0 += 32) {
    const size_t kb = (size_t)k0 * 2;
    ASYNC16(gA + (size_t)(bm + r0) * rowbytes + kb + c0, lA + wave * 2048);
    ASYNC16(gA + (size_t)(bm + r1) * rowbytes + kb + c1, lA + wave * 2048 + 1024);
    ASYNC16(gB + (size_t)(bn + r0) * rowbytes + kb + c0, lB + wave * 2048);
    ASYNC16(gB + (size_t)(bn + r1) * rowbytes + kb + c1, lB + wave * 2048 + 1024);
    __syncthreads();

    bf16x8 af[4], bg[4];
#pragma unroll
    for (int i = 0; i < 4; ++i)
      af[i] = *(const bf16x8*)&sA[(wr + i * 16 + mrow) * 32 + koff];
#pragma unroll
    for (int j = 0; j < 4; ++j)
      bg[j] = *(const bf16x8*)&sB[(wc + j * 16 + mrow) * 32 + koff];

#pragma unroll
    for (int i = 0; i < 4; ++i)
#pragma unroll
      for (int j = 0; j < 4; ++j)
        acc[i][j] =
            __builtin_amdgcn_mfma_f32_16x16x32_bf16(af[i], bg[j], acc[i][j], 0, 0, 0);
    __syncthreads();
  }

  // epilogue: C/D layout col=lane&15, row=(lane>>4)*4+reg
  const int ccol = lane & 15;
  const int crow = (lane >> 4) * 4;
#pragma unroll
  for (int j = 0; j < 4; ++j) {
    const int col = bn + wc + j * 16 + ccol;
    const float bv = bias[col];
#pragma unroll
    for (int i = 0; i < 4; ++i) {
      const int row0 = bm + wr + i * 16 + crow;
#pragma unroll
      for (int r = 0; r < 4; ++r)
        out[(size_t)(row0 + r) * ODIM + col] = acc[i][j][r] + bv;
    }
  }
}

extern "C" void kernel_launch(void* const* d_in, const int* in_sizes, int n_in,
                              void* d_out, int out_size, void* d_ws, size_t ws_size,
                              hipStream_t stream) {
  (void)in_sizes; (void)n_in; (void)out_size; (void)ws_size;
  const float* x = (const float*)d_in[0];
  const float* sp = (const float*)d_in[1];
  float* out = (float*)d_out;
  char* ws = (char*)d_ws;

  bf16* Pm = (bf16*)(ws + WS_P);
  bf16* CBm = (bf16*)(ws + WS_CB);
  float* bias = (float*)(ws + WS_BIAS);
  float* pmin = (float*)(ws + WS_PMIN);
  float* pmax = (float*)(ws + WS_PMAX);
  float* minv = (float*)(ws + WS_MINV);
  float* scale = (float*)(ws + WS_SCALE);

  hipMemsetAsync(bias, 0, ODIM * sizeof(float), stream);
  k_minmax_part<<<dim3(4, 64), 256, 0, stream>>>(x, pmin, pmax);
  k_minmax_final<<<4, 256, 0, stream>>>(pmin, pmax, minv, scale);
  k_powers<<<(BATCH * (DIM / 4)) / 256, 256, 0, stream>>>(x, minv, scale, Pm);
  k_coeffs<<<dim3(4, ODIM), 256, 0, stream>>>(sp, CBm, bias);
  k_gemm<<<dim3(32, 8), 256, 0, stream>>>(Pm, CBm, bias, out);
}

// Round 2
// 174.708 us; speedup vs baseline: 1.1100x; 1.1100x over previous
//
#include <hip/hip_runtime.h>
#include <hip/hip_bf16.h>
#include <stdint.h>
#include <stddef.h>

typedef __bf16 bf16;
typedef __attribute__((ext_vector_type(4))) __bf16 bf16x4;
typedef __attribute__((ext_vector_type(8))) __bf16 bf16x8;
typedef __attribute__((ext_vector_type(4))) float f32x4;

#define BATCH 4096
#define DIM 1024
#define ODIM 1024
#define K3 3072   // 3 * DIM (x^3 | x^2 | x)

// workspace layout (bytes)
#define WS_P      0          // bf16 [4096][3072] = 25165824
#define WS_CB     25165824   // bf16 [1024][3072] = 6291456
#define WS_BIAS   31457280   // f32  [1024]
#define WS_PMIN   31461376   // f32  [64][1024]
#define WS_PMAX   31723520   // f32  [64][1024]
#define WS_MINV   31985664   // f32  [1024]
#define WS_SCALE  31989760   // f32  [1024]

#define ASYNC16(g, l)                                                          \
  __builtin_amdgcn_global_load_lds(                                            \
      (__attribute__((address_space(1))) void*)(g),                            \
      (__attribute__((address_space(3))) void*)(l), 16, 0, 0)

// ---- kernel 1: per-chunk column min/max (64 chunks of 64 rows) ----
__global__ void k_minmax_part(const float* __restrict__ x,
                              float* __restrict__ pmin,
                              float* __restrict__ pmax) {
  int col = blockIdx.x * 256 + threadIdx.x;
  int ch = blockIdx.y;
  const float* p = x + (size_t)ch * 64 * DIM + col;
  float mn = 1e30f, mx = -1e30f;
#pragma unroll 8
  for (int r = 0; r < 64; ++r) {
    float v = p[(size_t)r * DIM];
    mn = fminf(mn, v);
    mx = fmaxf(mx, v);
  }
  pmin[ch * DIM + col] = mn;
  pmax[ch * DIM + col] = mx;
}

// ---- kernel 2: final reduce + scale ----
__global__ void k_minmax_final(const float* __restrict__ pmin,
                               const float* __restrict__ pmax,
                               float* __restrict__ minv,
                               float* __restrict__ scale) {
  int col = blockIdx.x * 256 + threadIdx.x;
  float mn = 1e30f, mx = -1e30f;
#pragma unroll 8
  for (int ch = 0; ch < 64; ++ch) {
    mn = fminf(mn, pmin[ch * DIM + col]);
    mx = fmaxf(mx, pmax[ch * DIM + col]);
  }
  minv[col] = mn;
  scale[col] = 1.0f / (mx - mn);
}

// ---- kernel 3 (fused): powers (blocks 0..4095) + coeff reduce (blocks 4096..5119)
__global__ void k_prep(const float* __restrict__ x,
                       const float* __restrict__ minv,
                       const float* __restrict__ scale,
                       bf16* __restrict__ P,
                       const float* __restrict__ sp,
                       bf16* __restrict__ CB,
                       float* __restrict__ bias) {
  __shared__ float red[4];
  const int t = threadIdx.x;
  if (blockIdx.x < BATCH) {
    // --- powers: normalized x -> bf16 P[b][p*1024+d] ---
    const int b = blockIdx.x;
    const int d = t << 2;
    f32x4 xv = *(const f32x4*)(x + (size_t)b * DIM + d);
    f32x4 mn = *(const f32x4*)(minv + d);
    f32x4 sc = *(const f32x4*)(scale + d);
    bf16x4 o3, o2, o1;
#pragma unroll
    for (int j = 0; j < 4; ++j) {
      float xn = (xv[j] - mn[j]) * sc[j];
      float x2 = xn * xn;
      float x3 = x2 * xn;
      o3[j] = (bf16)x3;
      o2[j] = (bf16)x2;
      o1[j] = (bf16)xn;
    }
    size_t base = (size_t)b * K3 + d;
    *(bf16x4*)(P + base) = o3;
    *(bf16x4*)(P + base + 1024) = o2;
    *(bf16x4*)(P + base + 2048) = o1;
  } else {
    // --- coeffs: sum spline_coeffs over s -> bf16 CB[o][p*1024+d], bias[o] ---
    const int o = blockIdx.x - BATCH;
    const int d = t << 2;
    f32x4 s[4];
#pragma unroll
    for (int dd = 0; dd < 4; ++dd) {
      const float* p = sp + ((size_t)o * DIM + d + dd) * 16;  // [s=4][4]
      f32x4 acc = *(const f32x4*)(p);
      acc += *(const f32x4*)(p + 4);
      acc += *(const f32x4*)(p + 8);
      acc += *(const f32x4*)(p + 12);
      s[dd] = acc;
    }
    size_t cb = (size_t)o * K3 + d;
    bf16x4 c0 = {(bf16)s[0][0], (bf16)s[1][0], (bf16)s[2][0], (bf16)s[3][0]};
    bf16x4 c1 = {(bf16)s[0][1], (bf16)s[1][1], (bf16)s[2][1], (bf16)s[3][1]};
    bf16x4 c2 = {(bf16)s[0][2], (bf16)s[1][2], (bf16)s[2][2], (bf16)s[3][2]};
    *(bf16x4*)(CB + cb) = c0;
    *(bf16x4*)(CB + cb + 1024) = c1;
    *(bf16x4*)(CB + cb + 2048) = c2;
    float v = s[0][3] + s[1][3] + s[2][3] + s[3][3];
#pragma unroll
    for (int off = 32; off > 0; off >>= 1) v += __shfl_down(v, off, 64);
    int lane = t & 63, w = t >> 6;
    if (lane == 0) red[w] = v;
    __syncthreads();
    if (t == 0) bias[o] = red[0] + red[1] + red[2] + red[3];
  }
}

// ---- kernel 4: GEMM out[b][o] = P[b][:] . CB[o][:] + bias[o] ----
// 64x128 tile, BK=64, 256 threads = 4 waves (2x2 over 32x64 each),
// XOR-swizzled LDS (16B units, q ^= row&7) to kill bank conflicts.
#define BM 64
#define BN 128
#define BKE 64  // K elems per iter; row = BKE*2 = 128 bytes = 8 x 16B units
__global__ __launch_bounds__(256, 2) void k_gemm(const bf16* __restrict__ P,
                                                 const bf16* __restrict__ CBm,
                                                 const float* __restrict__ bias,
                                                 float* __restrict__ out) {
  __shared__ bf16 sA[BM * BKE];  // 8 KB
  __shared__ bf16 sB[BN * BKE];  // 16 KB

  const int tid = threadIdx.x;
  const int wave = tid >> 6;
  const int lane = tid & 63;
  const int bm = blockIdx.x * BM;
  const int bn = blockIdx.y * BN;
  const int wr = (wave >> 1) * 32;  // wave row origin (M)
  const int wc = (wave & 1) * 64;   // wave col origin (N)

  const char* gA = (const char*)P;
  const char* gB = (const char*)CBm;
  char* lA = (char*)sA;
  char* lB = (char*)sB;
  const size_t rowbytes = (size_t)K3 * 2;  // 6144

  // staging address precompute: LDS slot (row, q) holds global 16B unit (row, q^(row&7))
  // issue i covers bytes [i*4096, i*4096+4096); off = i*4096 + tid*16
  int srowA[2], sgbA[2];
#pragma unroll
  for (int i = 0; i < 2; ++i) {
    int off = i * 4096 + tid * 16;
    int row = off >> 7;
    int q = (off >> 4) & 7;
    srowA[i] = row;
    sgbA[i] = (q ^ (row & 7)) * 16;
  }
  int srowB[4], sgbB[4];
#pragma unroll
  for (int i = 0; i < 4; ++i) {
    int off = i * 4096 + tid * 16;
    int row = off >> 7;
    int q = (off >> 4) & 7;
    srowB[i] = row;
    sgbB[i] = (q ^ (row & 7)) * 16;
  }

  f32x4 acc[2][4] = {};

  const int mrow = lane & 15;
  const int kq = lane >> 4;  // 16B-unit offset within a 32-elem k-window

  for (int k0 = 0; k0 < K3; k0 += BKE) {
    const size_t kb = (size_t)k0 * 2;
#pragma unroll
    for (int i = 0; i < 2; ++i)
      ASYNC16(gA + (size_t)(bm + srowA[i]) * rowbytes + kb + sgbA[i],
              lA + i * 4096 + wave * 1024);
#pragma unroll
    for (int i = 0; i < 4; ++i)
      ASYNC16(gB + (size_t)(bn + srowB[i]) * rowbytes + kb + sgbB[i],
              lB + i * 4096 + wave * 1024);
    __syncthreads();

    bf16x8 af[2][2], bg[2][4];
#pragma unroll
    for (int ks = 0; ks < 2; ++ks) {
#pragma unroll
      for (int i = 0; i < 2; ++i) {
        int row = wr + i * 16 + mrow;
        int sq = (ks * 4 + kq) ^ (row & 7);
        af[ks][i] = *(const bf16x8*)&sA[row * BKE + sq * 8];
      }
#pragma unroll
      for (int j = 0; j < 4; ++j) {
        int row = wc + j * 16 + mrow;
        int sq = (ks * 4 + kq) ^ (row & 7);
        bg[ks][j] = *(const bf16x8*)&sB[row * BKE + sq * 8];
      }
    }

#pragma unroll
    for (int ks = 0; ks < 2; ++ks)
#pragma unroll
      for (int i = 0; i < 2; ++i)
#pragma unroll
        for (int j = 0; j < 4; ++j)
          acc[i][j] = __builtin_amdgcn_mfma_f32_16x16x32_bf16(af[ks][i], bg[ks][j],
                                                              acc[i][j], 0, 0, 0);
    __syncthreads();
  }

  // epilogue: C/D layout col=lane&15, row=(lane>>4)*4+reg
  const int ccol = lane & 15;
  const int crow = (lane >> 4) * 4;
#pragma unroll
  for (int j = 0; j < 4; ++j) {
    const int col = bn + wc + j * 16 + ccol;
    const float bv = bias[col];
#pragma unroll
    for (int i = 0; i < 2; ++i) {
      const int row0 = bm + wr + i * 16 + crow;
#pragma unroll
      for (int r = 0; r < 4; ++r)
        out[(size_t)(row0 + r) * ODIM + col] = acc[i][j][r] + bv;
    }
  }
}

extern "C" void kernel_launch(void* const* d_in, const int* in_sizes, int n_in,
                              void* d_out, int out_size, void* d_ws, size_t ws_size,
                              hipStream_t stream) {
  (void)in_sizes; (void)n_in; (void)out_size; (void)ws_size;
  const float* x = (const float*)d_in[0];
  const float* sp = (const float*)d_in[1];
  float* out = (float*)d_out;
  char* ws = (char*)d_ws;

  bf16* Pm = (bf16*)(ws + WS_P);
  bf16* CBm = (bf16*)(ws + WS_CB);
  float* bias = (float*)(ws + WS_BIAS);
  float* pmin = (float*)(ws + WS_PMIN);
  float* pmax = (float*)(ws + WS_PMAX);
  float* minv = (float*)(ws + WS_MINV);
  float* scale = (float*)(ws + WS_SCALE);

  k_minmax_part<<<dim3(4, 64), 256, 0, stream>>>(x, pmin, pmax);
  k_minmax_final<<<4, 256, 0, stream>>>(pmin, pmax, minv, scale);
  k_prep<<<BATCH + ODIM, 256, 0, stream>>>(x, minv, scale, Pm, sp, CBm, bias);
  k_gemm<<<dim3(BATCH / BM, ODIM / BN), 256, 0, stream>>>(Pm, CBm, bias, out);
}

// Round 3
// 163.296 us; speedup vs baseline: 1.1876x; 1.0699x over previous
//
#include <hip/hip_runtime.h>
#include <hip/hip_bf16.h>
#include <stdint.h>
#include <stddef.h>

typedef __bf16 bf16;
typedef __attribute__((ext_vector_type(4))) __bf16 bf16x4;
typedef __attribute__((ext_vector_type(8))) __bf16 bf16x8;
typedef __attribute__((ext_vector_type(4))) float f32x4;

#define BATCH 4096
#define DIM 1024
#define ODIM 1024
#define K3 3072   // 3 * DIM (x^3 | x^2 | x)

// workspace layout (bytes)
#define WS_P      0          // bf16 [4096][3072] = 25165824
#define WS_CB     25165824   // bf16 [1024][3072] = 6291456
#define WS_BIAS   31457280   // f32  [1024]
#define WS_PMIN   31461376   // f32  [64][1024]
#define WS_PMAX   31723520   // f32  [64][1024]
#define WS_MINV   31985664   // f32  [1024]
#define WS_SCALE  31989760   // f32  [1024]

#define ASYNC16(g, l)                                                          \
  __builtin_amdgcn_global_load_lds(                                            \
      (__attribute__((address_space(1))) void*)(g),                            \
      (__attribute__((address_space(3))) void*)(l), 16, 0, 0)

// s_waitcnt imm: vmcnt[3:0]=bits3:0, expcnt=bits6:4, lgkmcnt=bits11:8, vmcnt[5:4]=bits15:14
// no-wait lgkm(15)/exp(7); wait vmcnt<=n
#define WAIT_VM(n) __builtin_amdgcn_s_waitcnt(0x0F00 | 0x0070 | ((n)&15) | ((((n)>>4)&3)<<14))
#define BARRIER()                     \
  do {                                \
    asm volatile("" ::: "memory");    \
    __builtin_amdgcn_s_barrier();     \
    asm volatile("" ::: "memory");    \
  } while (0)

// ---- kernel 1: per-chunk column min/max (64 chunks of 64 rows, f32x4 rows) ----
__global__ void k_minmax_part(const float* __restrict__ x,
                              float* __restrict__ pmin,
                              float* __restrict__ pmax) {
  const int t = threadIdx.x;       // 256 threads: cols 4t..4t+3
  const int ch = blockIdx.x;       // 64 chunks of 64 rows
  const float* p = x + (size_t)ch * 64 * DIM + (t << 2);
  f32x4 mn = {1e30f, 1e30f, 1e30f, 1e30f};
  f32x4 mx = {-1e30f, -1e30f, -1e30f, -1e30f};
#pragma unroll 8
  for (int r = 0; r < 64; ++r) {
    f32x4 v = *(const f32x4*)(p + (size_t)r * DIM);
#pragma unroll
    for (int j = 0; j < 4; ++j) {
      mn[j] = fminf(mn[j], v[j]);
      mx[j] = fmaxf(mx[j], v[j]);
    }
  }
  *(f32x4*)(pmin + ch * DIM + (t << 2)) = mn;
  *(f32x4*)(pmax + ch * DIM + (t << 2)) = mx;
}

// ---- kernel 2: final reduce + scale ----
__global__ void k_minmax_final(const float* __restrict__ pmin,
                               const float* __restrict__ pmax,
                               float* __restrict__ minv,
                               float* __restrict__ scale) {
  int col = blockIdx.x * 256 + threadIdx.x;
  float mn = 1e30f, mx = -1e30f;
#pragma unroll 8
  for (int ch = 0; ch < 64; ++ch) {
    mn = fminf(mn, pmin[ch * DIM + col]);
    mx = fmaxf(mx, pmax[ch * DIM + col]);
  }
  minv[col] = mn;
  scale[col] = 1.0f / (mx - mn);
}

// ---- kernel 3 (fused): powers (blocks 0..4095) + coeff reduce (blocks 4096..5119)
__global__ void k_prep(const float* __restrict__ x,
                       const float* __restrict__ minv,
                       const float* __restrict__ scale,
                       bf16* __restrict__ P,
                       const float* __restrict__ sp,
                       bf16* __restrict__ CB,
                       float* __restrict__ bias) {
  __shared__ float red[4];
  const int t = threadIdx.x;
  if (blockIdx.x < BATCH) {
    const int b = blockIdx.x;
    const int d = t << 2;
    f32x4 xv = *(const f32x4*)(x + (size_t)b * DIM + d);
    f32x4 mn = *(const f32x4*)(minv + d);
    f32x4 sc = *(const f32x4*)(scale + d);
    bf16x4 o3, o2, o1;
#pragma unroll
    for (int j = 0; j < 4; ++j) {
      float xn = (xv[j] - mn[j]) * sc[j];
      float x2 = xn * xn;
      float x3 = x2 * xn;
      o3[j] = (bf16)x3;
      o2[j] = (bf16)x2;
      o1[j] = (bf16)xn;
    }
    size_t base = (size_t)b * K3 + d;
    *(bf16x4*)(P + base) = o3;
    *(bf16x4*)(P + base + 1024) = o2;
    *(bf16x4*)(P + base + 2048) = o1;
  } else {
    const int o = blockIdx.x - BATCH;
    const int d = t << 2;
    f32x4 s[4];
#pragma unroll
    for (int dd = 0; dd < 4; ++dd) {
      const float* p = sp + ((size_t)o * DIM + d + dd) * 16;  // [s=4][4]
      f32x4 acc = *(const f32x4*)(p);
      acc += *(const f32x4*)(p + 4);
      acc += *(const f32x4*)(p + 8);
      acc += *(const f32x4*)(p + 12);
      s[dd] = acc;
    }
    size_t cb = (size_t)o * K3 + d;
    bf16x4 c0 = {(bf16)s[0][0], (bf16)s[1][0], (bf16)s[2][0], (bf16)s[3][0]};
    bf16x4 c1 = {(bf16)s[0][1], (bf16)s[1][1], (bf16)s[2][1], (bf16)s[3][1]};
    bf16x4 c2 = {(bf16)s[0][2], (bf16)s[1][2], (bf16)s[2][2], (bf16)s[3][2]};
    *(bf16x4*)(CB + cb) = c0;
    *(bf16x4*)(CB + cb + 1024) = c1;
    *(bf16x4*)(CB + cb + 2048) = c2;
    float v = s[0][3] + s[1][3] + s[2][3] + s[3][3];
#pragma unroll
    for (int off = 32; off > 0; off >>= 1) v += __shfl_down(v, off, 64);
    int lane = t & 63, w = t >> 6;
    if (lane == 0) red[w] = v;
    __syncthreads();
    if (t == 0) bias[o] = red[0] + red[1] + red[2] + red[3];
  }
}

// ---- kernel 4: GEMM out[b][o] = P[b][:] . CB[o][:] + bias[o] ----
// 128x128 tile, BK=64, 4 waves each 64x64 (4x4 frags of 16x16x32).
// Explicit double-buffered pipeline: stage tile k+1 async -> s_waitcnt vmcnt(8)
// (drains only tile k's loads; k+1's stay in flight across the barrier) ->
// raw s_barrier -> compute -> raw s_barrier. XOR-swizzled LDS (16B units).
#define BM 128
#define BN 128
#define BKE 64   // K elems per iter; row = 128 B = 8 x 16B units
#define NIT (K3 / BKE)  // 48
__global__ __launch_bounds__(256, 1) void k_gemm(const bf16* __restrict__ P,
                                                 const bf16* __restrict__ CBm,
                                                 const float* __restrict__ bias,
                                                 float* __restrict__ out) {
  __shared__ bf16 ldsm[2][2][BM * BKE];  // [buf][A/B][128*64] = 64 KB total

  const int tid = threadIdx.x;
  const int wave = tid >> 6;
  const int lane = tid & 63;
  const int bm = blockIdx.x * BM;
  const int bn = blockIdx.y * BN;
  const int wr = (wave >> 1) * 64;  // wave row origin (M)
  const int wc = (wave & 1) * 64;   // wave col origin (N)

  const size_t rowbytes = (size_t)K3 * 2;  // 6144

  // staging precompute: issue i covers LDS bytes [i*4096, i*4096+4096);
  // LDS slot (row, q) holds global 16B unit (row, q^(row&7)).
  const char* gAp[4];
  const char* gBp[4];
  int ldso[4];
#pragma unroll
  for (int i = 0; i < 4; ++i) {
    int off = i * 4096 + tid * 16;
    int row = off >> 7;          // 128B rows
    int q = (off >> 4) & 7;
    int gb = (q ^ (row & 7)) * 16;
    gAp[i] = (const char*)P + (size_t)(bm + row) * rowbytes + gb;
    gBp[i] = (const char*)CBm + (size_t)(bn + row) * rowbytes + gb;
    ldso[i] = i * 4096 + wave * 1024;  // wave-uniform base; HW adds lane*16
  }

  f32x4 acc[4][4] = {};

  const int mrow = lane & 15;
  const int kq = lane >> 4;  // 16B-unit index within a 32-elem k-window

#define STAGE(buf, kt)                                                        \
  do {                                                                        \
    const size_t kb_ = (size_t)(kt) * (BKE * 2);                              \
    char* lA_ = (char*)&ldsm[buf][0][0];                                      \
    char* lB_ = (char*)&ldsm[buf][1][0];                                      \
    _Pragma("unroll") for (int i_ = 0; i_ < 4; ++i_)                          \
        ASYNC16(gAp[i_] + kb_, lA_ + ldso[i_]);                               \
    _Pragma("unroll") for (int i_ = 0; i_ < 4; ++i_)                          \
        ASYNC16(gBp[i_] + kb_, lB_ + ldso[i_]);                               \
  } while (0)

#define COMPUTE(buf)                                                          \
  do {                                                                        \
    const bf16* sA_ = &ldsm[buf][0][0];                                       \
    const bf16* sB_ = &ldsm[buf][1][0];                                       \
    _Pragma("unroll") for (int ks = 0; ks < 2; ++ks) {                        \
      bf16x8 af[4], bg[4];                                                    \
      _Pragma("unroll") for (int i = 0; i < 4; ++i) {                         \
        int row = wr + i * 16 + mrow;                                         \
        int sq = (ks * 4 + kq) ^ (row & 7);                                   \
        af[i] = *(const bf16x8*)&sA_[row * BKE + sq * 8];                     \
      }                                                                       \
      _Pragma("unroll") for (int j = 0; j < 4; ++j) {                         \
        int row = wc + j * 16 + mrow;                                         \
        int sq = (ks * 4 + kq) ^ (row & 7);                                   \
        bg[j] = *(const bf16x8*)&sB_[row * BKE + sq * 8];                     \
      }                                                                       \
      _Pragma("unroll") for (int i = 0; i < 4; ++i)                           \
          _Pragma("unroll") for (int j = 0; j < 4; ++j)                       \
              acc[i][j] = __builtin_amdgcn_mfma_f32_16x16x32_bf16(            \
                  af[i], bg[j], acc[i][j], 0, 0, 0);                          \
    }                                                                         \
  } while (0)

  // prologue: tile 0 -> buf 0
  STAGE(0, 0);
#pragma unroll 2
  for (int kt = 0; kt < NIT - 1; ++kt) {
    const int cur = kt & 1;
    STAGE(cur ^ 1, kt + 1);  // prefetch next tile into other buffer
    WAIT_VM(8);              // drain ONLY tile kt's 8 issues
    BARRIER();
    COMPUTE(cur);
    BARRIER();               // all waves done reading buf[cur] before overwrite
  }
  // peeled last iteration
  WAIT_VM(0);
  BARRIER();
  COMPUTE((NIT - 1) & 1);

  // epilogue: C/D layout col=lane&15, row=(lane>>4)*4+reg
  const int ccol = lane & 15;
  const int crow = (lane >> 4) * 4;
#pragma unroll
  for (int j = 0; j < 4; ++j) {
    const int col = bn + wc + j * 16 + ccol;
    const float bv = bias[col];
#pragma unroll
    for (int i = 0; i < 4; ++i) {
      const int row0 = bm + wr + i * 16 + crow;
#pragma unroll
      for (int r = 0; r < 4; ++r)
        out[(size_t)(row0 + r) * ODIM + col] = acc[i][j][r] + bv;
    }
  }
#undef STAGE
#undef COMPUTE
}

extern "C" void kernel_launch(void* const* d_in, const int* in_sizes, int n_in,
                              void* d_out, int out_size, void* d_ws, size_t ws_size,
                              hipStream_t stream) {
  (void)in_sizes; (void)n_in; (void)out_size; (void)ws_size;
  const float* x = (const float*)d_in[0];
  const float* sp = (const float*)d_in[1];
  float* out = (float*)d_out;
  char* ws = (char*)d_ws;

  bf16* Pm = (bf16*)(ws + WS_P);
  bf16* CBm = (bf16*)(ws + WS_CB);
  float* bias = (float*)(ws + WS_BIAS);
  float* pmin = (float*)(ws + WS_PMIN);
  float* pmax = (float*)(ws + WS_PMAX);
  float* minv = (float*)(ws + WS_MINV);
  float* scale = (float*)(ws + WS_SCALE);

  k_minmax_part<<<64, 256, 0, stream>>>(x, pmin, pmax);
  k_minmax_final<<<4, 256, 0, stream>>>(pmin, pmax, minv, scale);
  k_prep<<<BATCH + ODIM, 256, 0, stream>>>(x, minv, scale, Pm, sp, CBm, bias);
  k_gemm<<<dim3(BATCH / BM, ODIM / BN), 256, 0, stream>>>(Pm, CBm, bias, out);
}